// Round 2
// baseline (150.279 us; speedup 1.0000x reference)
//
#include <hip/hip_runtime.h>
#include <hip/hip_bf16.h>
#include <math.h>

#define NN 512

// smearing constants
#define START 0.006737946999085467f            // exp(-5)
#define STEP  ((1.0f - START) * (1.0f/15.0f))  // linspace step
#define SB    (0.125f * (1.0f - START))
#define BETA  (1.0f/(SB*SB))
#define LOG2E 1.4426950408889634f
#define NB    (-(BETA)*LOG2E)                  // exp(-beta t^2) = exp2(NB t^2)

// ---------------------------------------------------------------------------
// k1a: stage-1 einsum partials. Grid 512 = 128 i-tiles(x4 rows) * 4 j-chunks.
// 256 thr = 64 j-slots * 4 c-quad lanes. Each lane: float4 K/Q loads, 4 i-rows
// share every K/Q fetch and every smearing exp.  Output: part1[i][jc][96]
// with 96 = (kq,b,c) = kq*48 + b*16 + c.
// ---------------------------------------------------------------------------
__global__ __launch_bounds__(256,2) void k1a(const float* __restrict__ x,
                                             const float* __restrict__ W,
                                             float* __restrict__ part1)
{
    const int it = blockIdx.x >> 2, jc = blockIdx.x & 3;
    const int i0 = it * 4;
    const int tid = threadIdx.x;
    const int s = tid >> 2, l = tid & 3;
    const int lane = tid & 63, wv = tid >> 6;

    __shared__ float s_part[4][4][96];   // [wave][lane-quad][flat]

    float xi[4][3];
    #pragma unroll
    for (int ii = 0; ii < 4; ++ii) {
        xi[ii][0] = x[(i0+ii)*3+0];
        xi[ii][1] = x[(i0+ii)*3+1];
        xi[ii][2] = x[(i0+ii)*3+2];
    }

    float acc[96];                       // [i][kq][b][e] = i*24+kq*12+b*4+e
    #pragma unroll
    for (int v = 0; v < 96; ++v) acc[v] = 0.f;

    const int jbase = jc * 128;
    for (int jt = 0; jt < 2; ++jt) {
        const int j = jbase + jt*64 + s;
        const float xj0 = x[j*3+0], xj1 = x[j*3+1], xj2 = x[j*3+2];

        float d[4][3], cutv[4], en[4];
        #pragma unroll
        for (int ii = 0; ii < 4; ++ii) {
            float d0 = xi[ii][0]-xj0, d1 = xi[ii][1]-xj1, d2 = xi[ii][2]-xj2;
            float nsq = fmaf(d0,d0, fmaf(d1,d1, fmaf(d2,d2, 1e-6f)));
            float rs  = __builtin_amdgcn_rsqf(nsq);
            float nrm = nsq * rs;        // sqrt(nsq)
            float inv = rs * rs;         // 1/nsq
            d[ii][0] = d0*inv; d[ii][1] = d1*inv; d[ii][2] = d2*inv;
            float cv = 0.f;
            if (nrm < 5.0f) cv = 0.5f*(__cosf(nrm*0.6283185307179586f)+1.0f);
            cutv[ii] = cv;
            en[ii]   = exp2f(-LOG2E * nrm);
        }

        const float4* kj = reinterpret_cast<const float4*>(W + j*256 + l*4);
        const float4* qj = reinterpret_cast<const float4*>(W + NN*256 + j*256 + l*4);

        float tk[4][4], tq[4][4];
        #pragma unroll
        for (int ii = 0; ii < 4; ++ii)
            #pragma unroll
            for (int e = 0; e < 4; ++e) { tk[ii][e] = 0.f; tq[ii][e] = 0.f; }

        #pragma unroll
        for (int r = 0; r < 16; ++r) {
            float4 k4 = kj[r*4];
            float4 q4 = qj[r*4];
            const float m = START + STEP * (float)r;
            #pragma unroll
            for (int ii = 0; ii < 4; ++ii) {
                float t = en[ii] - m;
                float e = exp2f(NB * t * t);
                tk[ii][0] = fmaf(e, k4.x, tk[ii][0]);
                tk[ii][1] = fmaf(e, k4.y, tk[ii][1]);
                tk[ii][2] = fmaf(e, k4.z, tk[ii][2]);
                tk[ii][3] = fmaf(e, k4.w, tk[ii][3]);
                tq[ii][0] = fmaf(e, q4.x, tq[ii][0]);
                tq[ii][1] = fmaf(e, q4.y, tq[ii][1]);
                tq[ii][2] = fmaf(e, q4.z, tq[ii][2]);
                tq[ii][3] = fmaf(e, q4.w, tq[ii][3]);
            }
        }

        #pragma unroll
        for (int ii = 0; ii < 4; ++ii) {
            const float w0 = cutv[ii]*d[ii][0];
            const float w1 = cutv[ii]*d[ii][1];
            const float w2 = cutv[ii]*d[ii][2];
            #pragma unroll
            for (int e = 0; e < 4; ++e) {
                acc[ii*24 +      e] = fmaf(w0, tk[ii][e], acc[ii*24 +      e]);
                acc[ii*24 +  4 + e] = fmaf(w1, tk[ii][e], acc[ii*24 +  4 + e]);
                acc[ii*24 +  8 + e] = fmaf(w2, tk[ii][e], acc[ii*24 +  8 + e]);
                acc[ii*24 + 12 + e] = fmaf(w0, tq[ii][e], acc[ii*24 + 12 + e]);
                acc[ii*24 + 16 + e] = fmaf(w1, tq[ii][e], acc[ii*24 + 16 + e]);
                acc[ii*24 + 20 + e] = fmaf(w2, tq[ii][e], acc[ii*24 + 20 + e]);
            }
        }
    }

    // reduce over 16 j-slots within each wave (lane bits 2..5)
    #pragma unroll
    for (int v = 0; v < 96; ++v) {
        float t = acc[v];
        t += __shfl_xor(t, 4);
        t += __shfl_xor(t, 8);
        t += __shfl_xor(t, 16);
        t += __shfl_xor(t, 32);
        if (lane < 4) s_part[wv][l][v] = t;
    }
    __syncthreads();

    for (int v = tid; v < 384; v += 256) {
        int i = v / 96, o = v - i*96;
        int kq = o / 48, rem = o - kq*48;
        int b = rem >> 4, c = rem & 15;
        int ll = c >> 2, e = c & 3;
        int f = i*24 + kq*12 + b*4 + e;
        float sum = s_part[0][ll][f] + s_part[1][ll][f]
                  + s_part[2][ll][f] + s_part[3][ll][f];
        part1[(i0+i)*384 + jc*96 + o] = sum;
    }
}

// ---------------------------------------------------------------------------
// k1b: per-i reduce partials -> att1 -> silu(W1) -> att2 row.  Grid 512.
// ---------------------------------------------------------------------------
__global__ __launch_bounds__(256) void k1b(const float* __restrict__ part1,
                                           const float* __restrict__ W1,
                                           const float* __restrict__ b1,
                                           const float* __restrict__ W2,
                                           float* __restrict__ att2)
{
    const int i = blockIdx.x;
    const int tid = threadIdx.x;
    __shared__ float s_bkq[96];
    __shared__ float s_att[256];
    __shared__ float s_z[16][16];
    __shared__ float s_a1[16];

    if (tid < 96) {
        const float* p = part1 + i*384 + tid;
        s_bkq[tid] = p[0] + p[96] + p[192] + p[288];
    }
    __syncthreads();

    {
        int h = tid >> 4, g = tid & 15;
        s_att[tid] = s_bkq[     h]*s_bkq[48+     g]
                   + s_bkq[16 + h]*s_bkq[48+16 + g]
                   + s_bkq[32 + h]*s_bkq[48+32 + g];
    }
    __syncthreads();

    {
        int h = tid & 15, seg = tid >> 4;
        const float* w1 = W1 + h*256 + seg*16;
        const float* a  = s_att + seg*16;
        float p = 0.f;
        #pragma unroll
        for (int k = 0; k < 16; ++k) p = fmaf(a[k], w1[k], p);
        s_z[seg][h] = p;
    }
    __syncthreads();

    if (tid < 16) {
        float z = b1[tid];
        #pragma unroll
        for (int seg = 0; seg < 16; ++seg) z += s_z[seg][tid];
        s_a1[tid] = z / (1.0f + __expf(-z));
    }
    __syncthreads();

    float a1[16];
    #pragma unroll
    for (int c = 0; c < 16; ++c) a1[c] = s_a1[c];
    #pragma unroll
    for (int p = 0; p < 4; ++p) {
        int o = tid + p*256;
        const float4* w2 = reinterpret_cast<const float4*>(W2 + o*16);
        float4 wa = w2[0], wb = w2[1], wc = w2[2], wd = w2[3];
        float accv = wa.x*a1[0] + wa.y*a1[1] + wa.z*a1[2] + wa.w*a1[3]
                   + wb.x*a1[4] + wb.y*a1[5] + wb.z*a1[6] + wb.w*a1[7]
                   + wc.x*a1[8] + wc.y*a1[9] + wc.z*a1[10]+ wc.w*a1[11]
                   + wd.x*a1[12]+ wd.y*a1[13]+ wd.z*a1[14]+ wd.w*a1[15];
        att2[i*1024 + o] = accv;
    }
}

// ---------------------------------------------------------------------------
// k2a: stage-3 right-term einsum partials + S partials.
// part2[i][jc][144]: 96 = (kq,b,c) like part1; 48 = S (r,b) at 96+r*3+b.
// ---------------------------------------------------------------------------
__global__ __launch_bounds__(256,2) void k2a(const float* __restrict__ x,
                                             const float* __restrict__ att2,
                                             float* __restrict__ part2)
{
    const int it = blockIdx.x >> 2, jc = blockIdx.x & 3;
    const int i0 = it * 4;
    const int tid = threadIdx.x;
    const int s = tid >> 2, l = tid & 3;
    const int lane = tid & 63, wv = tid >> 6;

    __shared__ float s_part[4][4][144];

    float xi[4][3];
    #pragma unroll
    for (int ii = 0; ii < 4; ++ii) {
        xi[ii][0] = x[(i0+ii)*3+0];
        xi[ii][1] = x[(i0+ii)*3+1];
        xi[ii][2] = x[(i0+ii)*3+2];
    }

    float acc[144];                      // [i]: 24 bkq (kq*12+b*4+e) + 12 S (24+rl*3+b)
    #pragma unroll
    for (int v = 0; v < 144; ++v) acc[v] = 0.f;

    const int jbase = jc * 128;
    for (int jt = 0; jt < 2; ++jt) {
        const int j = jbase + jt*64 + s;
        const float xj0 = x[j*3+0], xj1 = x[j*3+1], xj2 = x[j*3+2];

        float d[4][3], cutv[4], en[4];
        #pragma unroll
        for (int ii = 0; ii < 4; ++ii) {
            float d0 = xi[ii][0]-xj0, d1 = xi[ii][1]-xj1, d2 = xi[ii][2]-xj2;
            float nsq = fmaf(d0,d0, fmaf(d1,d1, fmaf(d2,d2, 1e-6f)));
            float rs  = __builtin_amdgcn_rsqf(nsq);
            float nrm = nsq * rs;
            float inv = rs * rs;
            d[ii][0] = d0*inv; d[ii][1] = d1*inv; d[ii][2] = d2*inv;
            float cv = 0.f;
            if (nrm < 5.0f) cv = 0.5f*(__cosf(nrm*0.6283185307179586f)+1.0f);
            cutv[ii] = cv;
            en[ii]   = exp2f(-LOG2E * nrm);
        }

        const float4* rj = reinterpret_cast<const float4*>(att2 + j*1024 + 512 + l*4);

        float tk[4][4], tq[4][4];
        #pragma unroll
        for (int ii = 0; ii < 4; ++ii)
            #pragma unroll
            for (int e = 0; e < 4; ++e) { tk[ii][e] = 0.f; tq[ii][e] = 0.f; }

        #pragma unroll
        for (int r = 0; r < 16; ++r) {
            float4 k4 = rj[r*4];
            float4 q4 = rj[64 + r*4];
            const float m = START + STEP * (float)r;
            #pragma unroll
            for (int ii = 0; ii < 4; ++ii) {
                float t = en[ii] - m;
                float e = exp2f(NB * t * t);
                tk[ii][0] = fmaf(e, k4.x, tk[ii][0]);
                tk[ii][1] = fmaf(e, k4.y, tk[ii][1]);
                tk[ii][2] = fmaf(e, k4.z, tk[ii][2]);
                tk[ii][3] = fmaf(e, k4.w, tk[ii][3]);
                tq[ii][0] = fmaf(e, q4.x, tq[ii][0]);
                tq[ii][1] = fmaf(e, q4.y, tq[ii][1]);
                tq[ii][2] = fmaf(e, q4.z, tq[ii][2]);
                tq[ii][3] = fmaf(e, q4.w, tq[ii][3]);
                if ((r & 3) == l) {       // this lane owns r: S[i][r>>2][b]
                    float es = e * cutv[ii];
                    const int fb = ii*36 + 24 + (r>>2)*3;
                    acc[fb+0] = fmaf(es, d[ii][0], acc[fb+0]);
                    acc[fb+1] = fmaf(es, d[ii][1], acc[fb+1]);
                    acc[fb+2] = fmaf(es, d[ii][2], acc[fb+2]);
                }
            }
        }

        #pragma unroll
        for (int ii = 0; ii < 4; ++ii) {
            const float w0 = cutv[ii]*d[ii][0];
            const float w1 = cutv[ii]*d[ii][1];
            const float w2 = cutv[ii]*d[ii][2];
            #pragma unroll
            for (int e = 0; e < 4; ++e) {
                acc[ii*36 +      e] = fmaf(w0, tk[ii][e], acc[ii*36 +      e]);
                acc[ii*36 +  4 + e] = fmaf(w1, tk[ii][e], acc[ii*36 +  4 + e]);
                acc[ii*36 +  8 + e] = fmaf(w2, tk[ii][e], acc[ii*36 +  8 + e]);
                acc[ii*36 + 12 + e] = fmaf(w0, tq[ii][e], acc[ii*36 + 12 + e]);
                acc[ii*36 + 16 + e] = fmaf(w1, tq[ii][e], acc[ii*36 + 16 + e]);
                acc[ii*36 + 20 + e] = fmaf(w2, tq[ii][e], acc[ii*36 + 20 + e]);
            }
        }
    }

    #pragma unroll
    for (int v = 0; v < 144; ++v) {
        float t = acc[v];
        t += __shfl_xor(t, 4);
        t += __shfl_xor(t, 8);
        t += __shfl_xor(t, 16);
        t += __shfl_xor(t, 32);
        if (lane < 4) s_part[wv][l][v] = t;
    }
    __syncthreads();

    for (int v = tid; v < 576; v += 256) {
        int i = v / 144, o = v - i*144;
        int ll, f;
        if (o < 96) {
            int kq = o / 48, rem = o - kq*48;
            int b = rem >> 4, c = rem & 15;
            ll = c >> 2;
            f = i*36 + kq*12 + b*4 + (c & 3);
        } else {
            int oS = o - 96;
            int r = oS / 3, b = oS - r*3;
            ll = r & 3;
            f = i*36 + 24 + (r>>2)*3 + b;
        }
        float sum = s_part[0][ll][f] + s_part[1][ll][f]
                  + s_part[2][ll][f] + s_part[3][ll][f];
        part2[(i0+i)*576 + jc*144 + o] = sum;
    }
}

// ---------------------------------------------------------------------------
// k2b: reduce + separable left-term + att3 -> silu(W3) -> W4 -> out. Grid 512.
// ---------------------------------------------------------------------------
__global__ __launch_bounds__(256) void k2b(const float* __restrict__ att2,
                                           const float* __restrict__ part2,
                                           const float* __restrict__ W3,
                                           const float* __restrict__ b3,
                                           const float* __restrict__ W4,
                                           const float* __restrict__ b4,
                                           float* __restrict__ out)
{
    const int i = blockIdx.x;
    const int tid = threadIdx.x;
    __shared__ float s_red[144];
    __shared__ float s_att[256];
    __shared__ float s_z[16][16];
    __shared__ float s_a1[16];

    if (tid < 144) {
        const float* p = part2 + i*576 + tid;
        s_red[tid] = p[0] + p[144] + p[288] + p[432];
    }
    __syncthreads();

    if (tid < 96) {                      // left-term: bkq[c,b] += sum_r left[r,c]*S[r,b]
        int kq = tid / 48, rem = tid - kq*48;
        int b = rem >> 4, c = rem & 15;
        const float* lrow = att2 + i*1024 + kq*256 + c;
        float add = 0.f;
        #pragma unroll
        for (int r = 0; r < 16; ++r)
            add = fmaf(lrow[r*16], s_red[96 + r*3 + b], add);
        s_red[tid] += add;
    }
    __syncthreads();

    {
        int h = tid >> 4, g = tid & 15;
        s_att[tid] = s_red[     h]*s_red[48+     g]
                   + s_red[16 + h]*s_red[48+16 + g]
                   + s_red[32 + h]*s_red[48+32 + g];
    }
    __syncthreads();

    {
        int h = tid & 15, seg = tid >> 4;
        const float* w3 = W3 + h*256 + seg*16;
        const float* a  = s_att + seg*16;
        float p = 0.f;
        #pragma unroll
        for (int k = 0; k < 16; ++k) p = fmaf(a[k], w3[k], p);
        s_z[seg][h] = p;
    }
    __syncthreads();

    if (tid < 16) {
        float z = b3[tid];
        #pragma unroll
        for (int seg = 0; seg < 16; ++seg) z += s_z[seg][tid];
        s_a1[tid] = z / (1.0f + __expf(-z));
    }
    __syncthreads();

    if (tid == 0) {
        float accv = b4[0];
        #pragma unroll
        for (int c = 0; c < 16; ++c) accv = fmaf(s_a1[c], W4[c], accv);
        out[i] = accv;
    }
}

extern "C" void kernel_launch(void* const* d_in, const int* in_sizes, int n_in,
                              void* d_out, int out_size, void* d_ws, size_t ws_size,
                              hipStream_t stream) {
    (void)in_sizes; (void)n_in; (void)out_size; (void)ws_size;
    const float* x  = (const float*)d_in[0];
    const float* W  = (const float*)d_in[1];
    const float* W1 = (const float*)d_in[2];
    const float* b1 = (const float*)d_in[3];
    const float* W2 = (const float*)d_in[4];
    const float* W3 = (const float*)d_in[5];
    const float* b3 = (const float*)d_in[6];
    const float* W4 = (const float*)d_in[7];
    const float* b4 = (const float*)d_in[8];

    float* att2  = (float*)d_ws;            // 512*1024
    float* part1 = att2 + 512*1024;         // 512*384
    float* part2 = part1 + 512*384;         // 512*576
    float* out   = (float*)d_out;

    k1a<<<512, 256, 0, stream>>>(x, W, part1);
    k1b<<<512, 256, 0, stream>>>(part1, W1, b1, W2, att2);
    k2a<<<512, 256, 0, stream>>>(x, att2, part2);
    k2b<<<512, 256, 0, stream>>>(att2, part2, W3, b3, W4, b4, out);
}